// Round 6
// baseline (3884.928 us; speedup 1.0000x reference)
//
#include <hip/hip_runtime.h>
#include <hip/hip_fp16.h>

#define Sn 128
#define Bn 64
#define Hn 512
#define Vn 100
#define TSn 31   // T-1 steps

typedef unsigned int   u32;
typedef unsigned short u16;
typedef _Float16 f16x2 __attribute__((ext_vector_type(2)));
typedef _Float16 f16x8 __attribute__((ext_vector_type(8)));
typedef float    f32x4 __attribute__((ext_vector_type(4)));

// ---- ws byte offsets (~5.22 MB) ----
#define OFF_WEMB  0ull          // fp16 [V][H]
#define OFF_WCOMB 102400ull     // fp16 [H][2H]
#define OFF_WIH   1150976ull    // fp16 [3H][H]
#define OFF_WHH   2723840ull    // fp16 [3H][H]
#define OFF_WOUT  4296704ull    // fp16 [V][H]
#define OFF_PCTX  4399104ull    // u32  [8][64][256]  fp16-pair ctx partials
#define OFF_PML   4923392ull    // f32  [8][64][2]    (m,l) partials
#define OFF_XEX   4927488ull    // u16  [64][512]     x
#define OFF_HEXF  4993024ull    // f32  [64][512]     h (fp32 master)
#define OFF_HEXH  5124096ull    // u16  [64][512]     h (fp16)
#define OFF_LLOG  5189632ull    // f32  [64][112]     raw logits
#define OFF_CNT   5218304ull    // u32  [3][9][16]    barrier counters (64B-padded)

__device__ __forceinline__ u16 f2h(float f){ _Float16 h=(_Float16)f; return __builtin_bit_cast(u16,h); }
__device__ __forceinline__ float2 h2f(u32 u){ f16x2 h=__builtin_bit_cast(f16x2,u); return make_float2((float)h.x,(float)h.y); }
__device__ __forceinline__ u32 pack2h(float a, float b){ return (u32)f2h(a) | ((u32)f2h(b) << 16); }

__device__ __forceinline__ float fast_tanh(float x){
    float e = __expf(2.0f*x);
    return 1.0f - 2.0f/(e + 1.0f);
}
__device__ __forceinline__ float fast_sigmoid(float x){ return 1.0f/(1.0f + __expf(-x)); }

__device__ __forceinline__ float wave_sum(float v){
#pragma unroll
    for (int o = 32; o; o >>= 1) v += __shfl_xor(v, o);
    return v;
}
__device__ __forceinline__ float wave_max(float v){
#pragma unroll
    for (int o = 32; o; o >>= 1) v = fmaxf(v, __shfl_xor(v, o));
    return v;
}

// volatile (L2-bypassing) 16B load as 4 dwords
__device__ __forceinline__ uint4 vload_u4(const u32* p){
    const volatile u32* q = (const volatile u32*)p;
    uint4 r; r.x=q[0]; r.y=q[1]; r.z=q[2]; r.w=q[3]; return r;
}
__device__ __forceinline__ f16x8 vfrag(const u16* p){        // LLC data (x, h)
    return __builtin_bit_cast(f16x8, vload_u4((const u32*)p));
}
__device__ __forceinline__ f16x8 frag_l2(const u16* p){      // L2-cached weights
    return __builtin_bit_cast(f16x8, *(const uint4*)p);
}
__device__ __forceinline__ f32x4 mfma16(f16x8 a, f16x8 b, f32x4 c){
    return __builtin_amdgcn_mfma_f32_16x16x32_f16(a, b, c, 0, 0, 0);
}

// ---- 2-level global barrier over 256 blocks (8 XCD counters -> top), monotonic ----
__device__ __forceinline__ void gbar_arrive(u32* CNT, int phase, int x, u32 round){
    asm volatile("s_waitcnt vmcnt(0)" ::: "memory");   // drain this wave's stores to LLC
    __syncthreads();                                   // all waves drained
    if (threadIdx.x == 0){
        u32* cx = CNT + (phase*9 + x)*16;
        u32* ct = CNT + (phase*9 + 8)*16;
        u32 old = __hip_atomic_fetch_add(cx, 1u, __ATOMIC_RELAXED, __HIP_MEMORY_SCOPE_AGENT);
        if (old == round*32u - 1u)    // last of this XCD's 32 blocks
            __hip_atomic_fetch_add(ct, 1u, __ATOMIC_RELAXED, __HIP_MEMORY_SCOPE_AGENT);
    }
}
__device__ __forceinline__ void gbar_wait(u32* CNT, int phase, u32 round){
    if (threadIdx.x == 0){
        u32* ct = CNT + (phase*9 + 8)*16;
        u32 v;
        do { __builtin_amdgcn_s_sleep(1);
             v = __hip_atomic_load(ct, __ATOMIC_RELAXED, __HIP_MEMORY_SCOPE_AGENT);
        } while (v < round*8u);
    }
    __syncthreads();
}

// ---------------- pre-pass: weights fp32->fp16, zero h and counters ----------------
#define CONV(S,D,N)                                              \
    for (int i = t0; i < (N)/4; i += stride) {                   \
        float4 v = ((const float4*)(S))[i];                      \
        ushort4 o;                                               \
        o.x = f2h(v.x); o.y = f2h(v.y);                          \
        o.z = f2h(v.z); o.w = f2h(v.w);                          \
        ((ushort4*)(D))[i] = o;                                  \
    }

__global__ __launch_bounds__(256) void prep(
    const float* __restrict__ Wemb, const float* __restrict__ Wcomb,
    const float* __restrict__ Wih, const float* __restrict__ Whh,
    const float* __restrict__ Wout, char* __restrict__ ws)
{
    const int t0 = blockIdx.x*256 + threadIdx.x;
    const int stride = gridDim.x*256;
    CONV(Wemb, (u16*)(ws+OFF_WEMB),  Vn*Hn)
    CONV(Wcomb,(u16*)(ws+OFF_WCOMB), Hn*2*Hn)
    CONV(Wih,  (u16*)(ws+OFF_WIH),   3*Hn*Hn)
    CONV(Whh,  (u16*)(ws+OFF_WHH),   3*Hn*Hn)
    CONV(Wout, (u16*)(ws+OFF_WOUT),  Vn*Hn)
    float* hexf = (float*)(ws+OFF_HEXF);
    for (int i = t0; i < Bn*Hn; i += stride) hexf[i] = 0.0f;
    u32* hexh = (u32*)(ws+OFF_HEXH);
    for (int i = t0; i < Bn*Hn/2; i += stride) hexh[i] = 0u;
    u32* cnt = (u32*)(ws+OFF_CNT);
    for (int i = t0; i < 3*9*16; i += stride) cnt[i] = 0u;
}

// ---------------- main kernel: 256 blocks x 512 thr ----------------
// block (x = bid&7 [XCD], lb = bid>>3 in [0,32)):
//   field: s-slice = [16x,16x+16), b-pair = {2lb, 2lb+1}
//   lb<16  : GRU tile (mt=lb>>2, jt=lb&3): j in [64x+16jt, +16)
//   lb>=16 : Wcomb tile (mt=(lb-16)>>2, nt=(lb-16)&3): x-rows [64x+16nt, +16)
//   x<7, lb in [24,28): logits tile (mt=lb-24, v-rows [16x,16x+16))
//   lb>=28 : lse for b = (x*4+(lb-28))*2 + {0,1}  (waves 5,6)
__global__ __launch_bounds__(512, 2) void bahdanau_decoder(
    const float* __restrict__ encf, const float* __restrict__ bcomb,
    const float* __restrict__ bih, const float* __restrict__ bhh,
    const float* __restrict__ bout, const float* __restrict__ wvat,
    const float* __restrict__ bvat, const int* __restrict__ tgt,
    float* __restrict__ out, char* __restrict__ ws)
{
    const u16* Wemb_h  = (const u16*)(ws + OFF_WEMB);
    const u16* Wcomb_h = (const u16*)(ws + OFF_WCOMB);
    const u16* Wih_h   = (const u16*)(ws + OFF_WIH);
    const u16* Whh_h   = (const u16*)(ws + OFF_WHH);
    const u16* Wout_h  = (const u16*)(ws + OFF_WOUT);
    u32*   PCTX = (u32*)(ws + OFF_PCTX);
    float* PML  = (float*)(ws + OFF_PML);
    u16*   XEX  = (u16*)(ws + OFF_XEX);
    float* HEXF = (float*)(ws + OFF_HEXF);
    u16*   HEXH = (u16*)(ws + OFF_HEXH);
    float* LLOG = (float*)(ws + OFF_LLOG);
    u32*   CNT  = (u32*)(ws + OFF_CNT);

    __shared__ float scores_s[2][16];
    __shared__ float expw_s[2][16];
    __shared__ float accx_s[4][64][4];

    const int tid  = threadIdx.x;
    const int lane = tid & 63;
    const int wid  = tid >> 6;          // 0..7
    const int bid  = blockIdx.x;
    const int x    = bid & 7;
    const int lb   = bid >> 3;
    const int col  = lane & 15;         // MFMA n / A-row sel
    const int kq   = lane >> 4;         // 0..3

    const bool isGru = (lb < 16);
    const int  lbl   = isGru ? lb : (lb - 16);
    const int  mtG   = lbl >> 2, jt = lbl & 3;
    const bool isLog = (x < 7) && (lb >= 24) && (lb < 28);
    const bool isLse = (lb >= 28);

    // loop-invariant vat slice (lane covers k = 8*lane..8*lane+8)
    const float4 wva = ((const float4*)wvat)[2*lane];
    const float4 wvb = ((const float4*)wvat)[2*lane+1];
    const float bv = bvat[0];

    for (int t = 0; t < TSn; ++t) {
        const u32 rnd = (u32)(t + 1);

        // ================= P_A =================
        // (1) scores: wave w -> b = 2lb + (w&1), 4 s rows
        {
            const int bl = wid & 1, b = 2*lb + bl;
            float hs[8];
            const volatile float* hp = HEXF + (size_t)b*Hn + 8*lane;
#pragma unroll
            for (int i2 = 0; i2 < 8; ++i2) hs[i2] = hp[i2];
#pragma unroll
            for (int i2 = 0; i2 < 4; ++i2) {
                const int s = x*16 + (wid>>1) + 4*i2;
                const float* ep = encf + ((size_t)s*Bn + b)*Hn + 8*lane;
                const float4 ea = *(const float4*)ep;
                const float4 eb = *(const float4*)(ep + 4);
                float acc = fast_tanh(ea.x+hs[0])*wva.x + fast_tanh(ea.y+hs[1])*wva.y
                          + fast_tanh(ea.z+hs[2])*wva.z + fast_tanh(ea.w+hs[3])*wva.w
                          + fast_tanh(eb.x+hs[4])*wvb.x + fast_tanh(eb.y+hs[5])*wvb.y
                          + fast_tanh(eb.z+hs[6])*wvb.z + fast_tanh(eb.w+hs[7])*wvb.w;
                acc = wave_sum(acc);
                if (lane == 0) scores_s[bl][(wid>>1) + 4*i2] = acc + bv;
            }
        }
        __syncthreads();
        // (2) local softmax partials for the 2 b
        if (wid < 2) {
            const int bl = wid, b = 2*lb + bl;
            const float sc = (lane < 16) ? scores_s[bl][lane] : -3.0e38f;
            const float m = wave_max(sc);
            const float ev = (lane < 16) ? __expf(sc - m) : 0.0f;
            const float l = wave_sum(ev);
            if (lane < 16) expw_s[bl][lane] = ev;
            if (lane == 0) {
                volatile float* pm = PML + ((size_t)x*Bn + b)*2;
                pm[0] = m; pm[1] = l;
            }
        }
        __syncthreads();
        // (3) pctx partials: wave w -> (b = 2lb+(w&1), k-chunk = w>>1), 2 k per lane
        {
            const int bl = wid & 1, b = 2*lb + bl, kc = wid >> 1;
            const float* ep = encf + ((size_t)(x*16)*Bn + b)*Hn + kc*128 + 2*lane;
            float a0 = 0.0f, a1 = 0.0f;
#pragma unroll
            for (int s = 0; s < 16; ++s) {
                const float w = expw_s[bl][s];
                const float2 e = *(const float2*)(ep + (size_t)s*Bn*Hn);
                a0 += w*e.x; a1 += w*e.y;
            }
            ((volatile u32*)PCTX)[((size_t)x*Bn + b)*256 + kc*64 + lane] = pack2h(a0, a1);
        }
        // (4) gh GEMM (GRU blocks, waves 0-2 = gates r,z,n), A = h(fp16, LLC), B = Whh(L2)
        f32x4 accR = {0,0,0,0}, accZ = {0,0,0,0}, ghN = {0,0,0,0}, giN = {0,0,0,0};
        if (isGru && wid < 3) {
            const int grow = wid*Hn + x*64 + jt*16 + col;
            const u16* wb = Whh_h + (size_t)grow*Hn + 8*kq;
            const u16* ha = HEXH + (size_t)(mtG*16 + col)*Hn + 8*kq;
            f32x4 acc = {0,0,0,0};
#pragma unroll
            for (int kf = 0; kf < 16; ++kf)
                acc = mfma16(vfrag(ha + 32*kf), frag_l2(wb + 32*kf), acc);
            if (wid == 0) accR = acc; else if (wid == 1) accZ = acc; else ghN = acc;
        }
        // (4b) raw logits of current h (output index t-1)
        if (isLog && wid == 4) {
            const int mt = lb - 24;
            const int v = x*16 + col;
            const int vrow = (v < Vn) ? v : 0;
            const u16* wb = Wout_h + (size_t)vrow*Hn + 8*kq;
            const u16* ha = HEXH + (size_t)(mt*16 + col)*Hn + 8*kq;
            f32x4 acc = {0,0,0,0};
#pragma unroll
            for (int kf = 0; kf < 16; ++kf)
                acc = mfma16(vfrag(ha + 32*kf), frag_l2(wb + 32*kf), acc);
            if (v < Vn) {
#pragma unroll
                for (int e = 0; e < 4; ++e) {
                    const int b2 = mt*16 + 4*kq + e;
                    ((volatile float*)LLOG)[(size_t)b2*112 + v] = acc[e] + bout[v];
                }
            }
        }
        gbar_arrive(CNT, 0, x, rnd);
        // B1 shadow: prefetch Wih B-frags for P_C
        f16x8 wih_f[16];
        if (isGru && wid < 3) {
            const int grow = wid*Hn + x*64 + jt*16 + col;
            const u16* wb = Wih_h + (size_t)grow*Hn + 8*kq;
#pragma unroll
            for (int kf = 0; kf < 16; ++kf) wih_f[kf] = frag_l2(wb + 32*kf);
        }
        gbar_wait(CNT, 0, rnd);

        // ================= P_B =================
        if (!isGru && wid == 3) {
            // Wcomb tile (mtG, nt=jt): x[b, j] = relu([emb;ctx] @ Wcomb[j,:])
            const int bA = mtG*16 + col;                 // A row
            const int sym = tgt[t*Bn + bA];
            const u16* ea = Wemb_h + (size_t)sym*Hn + 8*kq;
            const int xj = x*64 + jt*16 + col;           // B row / output col
            const u16* wb = Wcomb_h + (size_t)xj*2*Hn + 8*kq;
            // flash params for bA
            float mq[8], fq[8];
#pragma unroll
            for (int q2 = 0; q2 < 8; ++q2)
                mq[q2] = ((volatile float*)PML)[((size_t)q2*Bn + bA)*2];
            float M = mq[0];
#pragma unroll
            for (int q2 = 1; q2 < 8; ++q2) M = fmaxf(M, mq[q2]);
            float L = 0.0f;
#pragma unroll
            for (int q2 = 0; q2 < 8; ++q2) {
                const float lq = ((volatile float*)PML)[((size_t)q2*Bn + bA)*2 + 1];
                fq[q2] = __expf(mq[q2] - M);
                L += fq[q2]*lq;
            }
            const float linv = 1.0f / L;
#pragma unroll
            for (int q2 = 0; q2 < 8; ++q2) fq[q2] *= linv;
            f32x4 acc = {0,0,0,0};
#pragma unroll
            for (int kf = 0; kf < 16; ++kf)          // emb half (k<512)
                acc = mfma16(frag_l2(ea + 32*kf), frag_l2(wb + 32*kf), acc);
            for (int kf = 0; kf < 16; ++kf) {        // ctx half
                float c[8] = {0,0,0,0,0,0,0,0};
#pragma unroll
                for (int q2 = 0; q2 < 8; ++q2) {
                    const uint4 u = vload_u4(PCTX + ((size_t)q2*Bn + bA)*256 + 16*kf + 4*kq);
                    const float f = fq[q2];
                    float2 p;
                    p = h2f(u.x); c[0] += f*p.x; c[1] += f*p.y;
                    p = h2f(u.y); c[2] += f*p.x; c[3] += f*p.y;
                    p = h2f(u.z); c[4] += f*p.x; c[5] += f*p.y;
                    p = h2f(u.w); c[6] += f*p.x; c[7] += f*p.y;
                }
                f16x8 af;
#pragma unroll
                for (int e2 = 0; e2 < 8; ++e2) af[e2] = (_Float16)c[e2];
                acc = mfma16(af, frag_l2(wb + Hn + 32*kf), acc);
            }
#pragma unroll
            for (int e = 0; e < 4; ++e) {
                const int bD = mtG*16 + 4*kq + e;
                ((volatile u16*)XEX)[(size_t)bD*Hn + xj] =
                    f2h(fmaxf(acc[e] + bcomb[xj], 0.0f));
            }
        }
        if (t > 0 && isLse && (wid == 5 || wid == 6)) {
            const int b = (x*4 + (lb - 28))*2 + (wid - 5);
            const volatile float* lp = LLOG + (size_t)b*112;
            const float l0 = lp[lane];
            const float l1 = (lane < 36) ? lp[64 + lane] : -3.0e38f;
            const float mx = wave_max(fmaxf(l0, l1));
            const float e0 = __expf(l0 - mx);
            const float e1 = (lane < 36) ? __expf(l1 - mx) : 0.0f;
            const float lse = mx + __logf(wave_sum(e0 + e1));
            float* op = out + ((size_t)b*TSn + (t-1))*Vn;
            op[lane] = l0 - lse;
            if (lane < 36) op[64 + lane] = l1 - lse;
        }
        gbar_arrive(CNT, 1, x, rnd);
        gbar_wait(CNT, 1, rnd);

        // ================= P_C =================
        if (isGru) {
            if (wid < 3) {
                const u16* xa = XEX + (size_t)(mtG*16 + col)*Hn + 8*kq;
                f32x4 acc = (wid == 0) ? accR : (wid == 1) ? accZ : giN;
#pragma unroll
                for (int kf = 0; kf < 16; ++kf)
                    acc = mfma16(vfrag(xa + 32*kf), wih_f[kf], acc);
#pragma unroll
                for (int e = 0; e < 4; ++e) accx_s[wid][lane][e] = acc[e];
                if (wid == 2) {
#pragma unroll
                    for (int e = 0; e < 4; ++e) accx_s[3][lane][e] = ghN[e];
                }
            }
            __syncthreads();
            if (wid == 0) {
                const int j = x*64 + jt*16 + col;
                const float br  = bih[j]        + bhh[j];
                const float bz  = bih[Hn + j]   + bhh[Hn + j];
                const float bni = bih[2*Hn + j];
                const float bnh = bhh[2*Hn + j];
#pragma unroll
                for (int e = 0; e < 4; ++e) {
                    const int b2 = mtG*16 + 4*kq + e;
                    const float r = fast_sigmoid(accx_s[0][lane][e] + br);
                    const float z = fast_sigmoid(accx_s[1][lane][e] + bz);
                    const float n = fast_tanh(accx_s[2][lane][e] + bni
                                              + r*(accx_s[3][lane][e] + bnh));
                    const float hold = ((volatile float*)HEXF)[(size_t)b2*Hn + j];
                    const float hv = (1.0f - z)*n + z*hold;
                    ((volatile float*)HEXF)[(size_t)b2*Hn + j] = hv;
                    ((volatile u16*)HEXH)[(size_t)b2*Hn + j] = f2h(hv);
                }
            }
        }
        gbar_arrive(CNT, 2, x, rnd);
        gbar_wait(CNT, 2, rnd);
    }

    // ======= final logits round (output index TSn-1 from final h) =======
    if (isLog && wid == 4) {
        const int mt = lb - 24;
        const int v = x*16 + col;
        const int vrow = (v < Vn) ? v : 0;
        const u16* wb = Wout_h + (size_t)vrow*Hn + 8*kq;
        const u16* ha = HEXH + (size_t)(mt*16 + col)*Hn + 8*kq;
        f32x4 acc = {0,0,0,0};
#pragma unroll
        for (int kf = 0; kf < 16; ++kf)
            acc = mfma16(vfrag(ha + 32*kf), frag_l2(wb + 32*kf), acc);
        if (v < Vn) {
#pragma unroll
            for (int e = 0; e < 4; ++e) {
                const int b2 = mt*16 + 4*kq + e;
                ((volatile float*)LLOG)[(size_t)b2*112 + v] = acc[e] + bout[v];
            }
        }
    }
    gbar_arrive(CNT, 0, x, (u32)(TSn + 1));
    gbar_wait(CNT, 0, (u32)(TSn + 1));
    if (isLse && (wid == 5 || wid == 6)) {
        const int b = (x*4 + (lb - 28))*2 + (wid - 5);
        const volatile float* lp = LLOG + (size_t)b*112;
        const float l0 = lp[lane];
        const float l1 = (lane < 36) ? lp[64 + lane] : -3.0e38f;
        const float mx = wave_max(fmaxf(l0, l1));
        const float e0 = __expf(l0 - mx);
        const float e1 = (lane < 36) ? __expf(l1 - mx) : 0.0f;
        const float lse = mx + __logf(wave_sum(e0 + e1));
        float* op = out + ((size_t)b*TSn + (TSn-1))*Vn;
        op[lane] = l0 - lse;
        if (lane < 36) op[64 + lane] = l1 - lse;
    }
}

extern "C" void kernel_launch(void* const* d_in, const int* in_sizes, int n_in,
                              void* d_out, int out_size, void* d_ws, size_t ws_size,
                              hipStream_t stream) {
    const float* enc   = (const float*)d_in[0];
    const float* Wemb  = (const float*)d_in[1];
    const float* Wcomb = (const float*)d_in[2];
    const float* bcomb = (const float*)d_in[3];
    const float* Wih   = (const float*)d_in[4];
    const float* Whh   = (const float*)d_in[5];
    const float* bih   = (const float*)d_in[6];
    const float* bhh   = (const float*)d_in[7];
    const float* Wout  = (const float*)d_in[8];
    const float* bout  = (const float*)d_in[9];
    const float* wvat  = (const float*)d_in[10];
    const float* bvat  = (const float*)d_in[11];
    const int*   tgt   = (const int*)d_in[12];
    float* out = (float*)d_out;
    char*  ws  = (char*)d_ws;

    prep<<<256, 256, 0, stream>>>(Wemb, Wcomb, Wih, Whh, Wout, ws);

    void* args[] = { &enc, &bcomb, &bih, &bhh, &bout, &wvat, &bvat, &tgt, &out, &ws };
    hipLaunchCooperativeKernel((const void*)bahdanau_decoder,
                               dim3(256), dim3(512), args, 0, stream);
}

// Round 7
// 2129.034 us; speedup vs baseline: 1.8247x; 1.8247x over previous
//
#include <hip/hip_runtime.h>
#include <hip/hip_fp16.h>

#define Sn 128
#define Bn 64
#define Hn 512
#define Vn 100
#define TSn 31   // T-1 steps

typedef unsigned int   u32;
typedef unsigned short u16;
typedef _Float16 f16x2 __attribute__((ext_vector_type(2)));

// ---- ws byte offsets ----
#define OFF_ENC2  0ull          // fp16 [64][128][512]  8,388,608
#define OFF_WC2   8388608ull    // fp16 [512][512]        524,288  (ctx half of Wcomb)
#define OFF_WIH   8912896ull    // fp16 [1536][512]     1,572,864
#define OFF_WHH   10485760ull   // fp16 [1536][512]     1,572,864
#define OFF_WOUT  12058624ull   // fp16 [100][512]        102,400
#define OFF_EMB2  12161024ull   // f32  [100][512]        204,800  (Wc1 @ Wemb^T rows)
#define OFF_XEX   12365824ull   // u32  [64][256]          65,536
#define OFF_HEXF  12431360ull   // f32  [64][512]         131,072
#define OFF_HEXH  12562432ull   // u32  [64][256]          65,536
#define OFF_PLOG  12627968ull   // f32  [64][4][100]      102,400
#define OFF_CNT   12730368ull   // u32  [64][2][16]         8,192  (64B-padded counters)

__device__ __forceinline__ u16 f2h(float f){ _Float16 h=(_Float16)f; return __builtin_bit_cast(u16,h); }
__device__ __forceinline__ f16x2 uh2(u32 u){ return __builtin_bit_cast(f16x2,u); }
__device__ __forceinline__ float2 h2f(u32 u){ f16x2 h=uh2(u); return make_float2((float)h.x,(float)h.y); }
__device__ __forceinline__ u32 pack2h(float a, float b){ return (u32)f2h(a) | ((u32)f2h(b) << 16); }

#if __has_builtin(__builtin_amdgcn_fdot2)
__device__ __forceinline__ float dot2acc(u32 a, u32 b, float acc){
    return __builtin_amdgcn_fdot2(uh2(a), uh2(b), acc, false);
}
#else
__device__ __forceinline__ float dot2acc(u32 a, u32 b, float acc){
    float2 x=h2f(a), y=h2f(b); return acc + x.x*y.x + x.y*y.y;
}
#endif

__device__ __forceinline__ float dot8h(uint4 w, uint4 v, float acc){
    acc = dot2acc(w.x, v.x, acc); acc = dot2acc(w.y, v.y, acc);
    acc = dot2acc(w.z, v.z, acc); acc = dot2acc(w.w, v.w, acc);
    return acc;
}

__device__ __forceinline__ float fast_tanh(float x){
    float e = __expf(2.0f*x);
    return 1.0f - 2.0f/(e + 1.0f);
}
__device__ __forceinline__ float fast_sigmoid(float x){ return 1.0f/(1.0f + __expf(-x)); }

__device__ __forceinline__ float wave_sum(float v){
#pragma unroll
    for (int o = 32; o; o >>= 1) v += __shfl_xor(v, o);
    return v;
}
__device__ __forceinline__ float wave_max(float v){
#pragma unroll
    for (int o = 32; o; o >>= 1) v = fmaxf(v, __shfl_xor(v, o));
    return v;
}

// ---- scoped-atomic (AGENT) exchange: LLC-coherent, should stay LLC-cached ----
__device__ __forceinline__ void ast(u32* p, u32 v){
    __hip_atomic_store(p, v, __ATOMIC_RELAXED, __HIP_MEMORY_SCOPE_AGENT);
}
__device__ __forceinline__ u32 ald(u32* p){
    return __hip_atomic_load(p, __ATOMIC_RELAXED, __HIP_MEMORY_SCOPE_AGENT);
}
__device__ __forceinline__ void astf(float* p, float v){
    __hip_atomic_store((u32*)p, __builtin_bit_cast(u32, v), __ATOMIC_RELAXED, __HIP_MEMORY_SCOPE_AGENT);
}
__device__ __forceinline__ float aldf(float* p){
    return __builtin_bit_cast(float, __hip_atomic_load((u32*)p, __ATOMIC_RELAXED, __HIP_MEMORY_SCOPE_AGENT));
}

// ---- 4-sibling barrier: data stores drained, then padded monotone counter ----
__device__ __forceinline__ void sib_arrive(u32* cnt){
    asm volatile("s_waitcnt vmcnt(0)" ::: "memory");   // drain this wave's stores
    __syncthreads();                                   // all waves drained
    if (threadIdx.x == 0)
        __hip_atomic_fetch_add(cnt, 1u, __ATOMIC_RELAXED, __HIP_MEMORY_SCOPE_AGENT);
}
__device__ __forceinline__ void sib_wait(u32* cnt, u32 target){
    if (threadIdx.x == 0) {
        while (__hip_atomic_load(cnt, __ATOMIC_RELAXED, __HIP_MEMORY_SCOPE_AGENT) < target)
            __builtin_amdgcn_s_sleep(1);
    }
    __syncthreads();
}

// ---------------- prep 1: fp32 -> fp16 conversions, enc transpose, zero counters ----------------
#define CONV(S,D,N)                                              \
    for (int i = t0; i < (N)/4; i += stride) {                   \
        float4 v = ((const float4*)(S))[i];                      \
        ushort4 o;                                               \
        o.x = f2h(v.x); o.y = f2h(v.y);                          \
        o.z = f2h(v.z); o.w = f2h(v.w);                          \
        ((ushort4*)(D))[i] = o;                                  \
    }

__global__ __launch_bounds__(256) void prep_conv(
    const float* __restrict__ enc, const float* __restrict__ Wcomb,
    const float* __restrict__ Wih, const float* __restrict__ Whh,
    const float* __restrict__ Wout, char* __restrict__ ws)
{
    const int t0 = blockIdx.x*256 + threadIdx.x;
    const int stride = gridDim.x*256;
    // enc [S][B][H] f32 -> [B][S][H] fp16
    {
        u16* de = (u16*)(ws + OFF_ENC2);
        for (int c = t0; c < Sn*Bn*Hn/4; c += stride) {
            const int h4 = c & 127;
            const int s  = (c >> 7) & 127;
            const int bb = c >> 14;
            float4 v = ((const float4*)enc)[(s*Bn + bb)*(Hn/4) + h4];
            ushort4 o;
            o.x = f2h(v.x); o.y = f2h(v.y); o.z = f2h(v.z); o.w = f2h(v.w);
            ((ushort4*)de)[c] = o;
        }
    }
    // Wc2[j][k] = Wcomb[j][512+k]
    {
        u16* dc = (u16*)(ws + OFF_WC2);
        for (int i = t0; i < Hn*Hn/4; i += stride) {
            const int j = i >> 7, kk = i & 127;
            float4 v = ((const float4*)Wcomb)[j*256 + 128 + kk];
            ushort4 o;
            o.x = f2h(v.x); o.y = f2h(v.y); o.z = f2h(v.z); o.w = f2h(v.w);
            ((ushort4*)dc)[i] = o;
        }
    }
    CONV(Wih,  (u16*)(ws+OFF_WIH),  3*Hn*Hn)
    CONV(Whh,  (u16*)(ws+OFF_WHH),  3*Hn*Hn)
    CONV(Wout, (u16*)(ws+OFF_WOUT), Vn*Hn)
    u32* cnt = (u32*)(ws + OFF_CNT);
    for (int i = t0; i < 64*2*16; i += stride) cnt[i] = 0u;
}

// ---------------- prep 2: EMB2[v][j] = sum_k Wcomb[j][k] * Wemb[v][k]  (f32) ----------------
__global__ __launch_bounds__(512) void prep_emb2(
    const float* __restrict__ Wemb, const float* __restrict__ Wcomb,
    char* __restrict__ ws)
{
    float* EMB2 = (float*)(ws + OFF_EMB2);
    const int w = threadIdx.x >> 6;           // 8 waves
    const int lane = threadIdx.x & 63;
    const int j = blockIdx.x*8 + w;           // 64 blocks x 8 j
    const float4* wc = (const float4*)(Wcomb + (size_t)j*2*Hn);   // first half (emb)
#pragma unroll
    for (int pass = 0; pass < 2; ++pass) {
        const int v = lane + 64*pass;
        if (v < Vn) {
            const float4* we = (const float4*)(Wemb + (size_t)v*Hn);
            float acc = 0.0f;
            for (int k4 = 0; k4 < 128; ++k4) {
                const float4 a = wc[k4], b = we[k4];
                acc += a.x*b.x + a.y*b.y + a.z*b.z + a.w*b.w;
            }
            EMB2[(size_t)v*Hn + j] = acc;
        }
    }
}

// ---------------- main: 256 blocks x 1024 thr; 4 siblings (j-quarter) per b ----------------
// xcd=bid&7, lb=bid>>3, q=xcd&3, b=2*lb+(xcd>>2).  2 group barriers/step.
__global__ __launch_bounds__(1024) void bahdanau_decoder(
    const float* __restrict__ bcomb, const float* __restrict__ bih,
    const float* __restrict__ bhh, const float* __restrict__ bout,
    const float* __restrict__ wvat, const float* __restrict__ bvat,
    const int* __restrict__ tgt, float* __restrict__ out, char* __restrict__ ws)
{
    const u16* WC2  = (const u16*)(ws + OFF_WC2);
    const u16* WIH  = (const u16*)(ws + OFF_WIH);
    const u16* WHH  = (const u16*)(ws + OFF_WHH);
    const u16* WOUT = (const u16*)(ws + OFF_WOUT);
    const float* EMB2 = (const float*)(ws + OFF_EMB2);
    u32*   XEX  = (u32*)(ws + OFF_XEX);
    float* HEXF = (float*)(ws + OFF_HEXF);
    u32*   HEXH = (u32*)(ws + OFF_HEXH);
    float* PLOG = (float*)(ws + OFF_PLOG);
    u32*   CNT  = (u32*)(ws + OFF_CNT);

    extern __shared__ __align__(16) u16 enc_lds[];   // [128][512] fp16, 131072 B
    __shared__ __align__(16) float h_full[Hn];       // fp32 master h
    __shared__ __align__(16) u32   hh32[Hn/2];       // fp16-pair h
    __shared__ __align__(16) u32   ctx32[Hn/2];      // fp16-pair ctx
    __shared__ __align__(16) u32   x32[Hn/2];        // fp16-pair x (assembled)
    __shared__ __align__(16) u16   xst[128];         // own x quarter
    __shared__ __align__(16) u16   hn16[128];        // own h_new quarter fp16
    __shared__ __align__(16) float scores_s[Sn];
    __shared__ __align__(16) float attnw_s[Sn];
    __shared__ __align__(16) float2 pctx_s[4][256];
    __shared__ __align__(16) float plog_s[112];

    const int tid  = threadIdx.x;
    const int lane = tid & 63;
    const int wid  = tid >> 6;              // 0..15
    const int bid  = blockIdx.x;
    const int xcd  = bid & 7;
    const int lb   = bid >> 3;
    const int q    = xcd & 3;               // j-quarter (XCD-resident weight slice)
    const int b    = 2*lb + (xcd >> 2);
    const int j0   = q*128;
    u32* cntA = CNT + (b*2 + 0)*16;
    u32* cntB = CNT + (b*2 + 1)*16;

    // enc slice -> LDS (resident all steps)
    {
        const uint4* src = (const uint4*)(ws + OFF_ENC2 + (size_t)b*Sn*Hn*2);
        for (int i = tid; i < Sn*Hn/8; i += 1024) ((uint4*)enc_lds)[i] = src[i];
    }
    if (tid < Hn) h_full[tid] = 0.0f;
    if (tid < Hn/2) hh32[tid] = 0u;
    const float4 Wa = ((const float4*)wvat)[2*lane];
    const float4 Wb = ((const float4*)wvat)[2*lane+1];
    const float bv = bvat[0];
    __syncthreads();

    for (int t = 0; t < TSn; ++t) {
        const u32 tgtc = 4u*(t+1);

        // ---- P1: scores (replicated): wave per s, 64-lane dot ----
        {
            const float4 Ha = ((const float4*)h_full)[2*lane];
            const float4 Hb = ((const float4*)h_full)[2*lane+1];
            for (int s = wid; s < Sn; s += 16) {
                const uint4 E = ((const uint4*)(enc_lds + s*Hn))[lane];
                const float2 e0 = h2f(E.x), e1 = h2f(E.y), e2 = h2f(E.z), e3 = h2f(E.w);
                float acc = fast_tanh(e0.x+Ha.x)*Wa.x + fast_tanh(e0.y+Ha.y)*Wa.y
                          + fast_tanh(e1.x+Ha.z)*Wa.z + fast_tanh(e1.y+Ha.w)*Wa.w
                          + fast_tanh(e2.x+Hb.x)*Wb.x + fast_tanh(e2.y+Hb.y)*Wb.y
                          + fast_tanh(e3.x+Hb.z)*Wb.z + fast_tanh(e3.y+Hb.w)*Wb.w;
                acc = wave_sum(acc);
                if (lane == 0) scores_s[s] = acc + bv;
            }
        }
        __syncthreads();

        // ---- P2: softmax over 128 (wave 0) ----
        if (wid == 0) {
            const float s0 = scores_s[lane], s1 = scores_s[lane+64];
            const float mx = wave_max(fmaxf(s0, s1));
            const float e0 = __expf(s0-mx), e1 = __expf(s1-mx);
            const float inv = 1.0f / wave_sum(e0 + e1);
            attnw_s[lane]    = e0 * inv;
            attnw_s[lane+64] = e1 * inv;
        }
        __syncthreads();

        // ---- P3: ctx (replicated): thread = (o-pair, s-chunk) ----
        {
            const int op = tid & 255, sc = tid >> 8;
            float ax = 0.0f, ay = 0.0f;
#pragma unroll 8
            for (int i2 = 0; i2 < 32; ++i2) {
                const int s = sc*32 + i2;
                const float a = attnw_s[s];
                const float2 ef = h2f(((const u32*)(enc_lds + s*Hn))[op]);
                ax += a*ef.x; ay += a*ef.y;
            }
            pctx_s[sc][op] = make_float2(ax, ay);
        }
        __syncthreads();
        if (tid < 256) {
            const float2 c0 = pctx_s[0][tid], c1 = pctx_s[1][tid];
            const float2 c2 = pctx_s[2][tid], c3 = pctx_s[3][tid];
            ctx32[tid] = pack2h(c0.x+c1.x+c2.x+c3.x, c0.y+c1.y+c2.y+c3.y);
        }
        __syncthreads();

        // ---- P4: x own quarter: x[j] = relu(EMB2[sym][j] + Wc2[j]·ctx + bcomb[j]) ----
        {
            const int sym = tgt[t*Bn + b];
            const uint4 C = ((const uint4*)ctx32)[lane];
            for (int jj = wid; jj < 128; jj += 16) {
                const int j = j0 + jj;
                const uint4 W = ((const uint4*)(WC2 + (size_t)j*Hn))[lane];
                float acc = dot8h(W, C, 0.0f);
                acc = wave_sum(acc);
                if (lane == 0)
                    xst[jj] = f2h(fmaxf(acc + EMB2[(size_t)sym*Hn + j] + bcomb[j], 0.0f));
            }
        }
        __syncthreads();
        if (wid == 0)
            ast(XEX + b*256 + q*64 + lane, (u32)xst[2*lane] | ((u32)xst[2*lane+1] << 16));
        sib_arrive(cntA);

        // ---- barrier-A shadow: gh dots (h-side GRU) for own j-slice ----
        float ghr[8], ghz[8], ghn[8];
        {
            const uint4 HH = ((const uint4*)hh32)[lane];
#pragma unroll
            for (int k = 0; k < 8; ++k) {
                const int j = j0 + wid*8 + k;
                const uint4 R = ((const uint4*)(WHH + (size_t)j*Hn))[lane];
                const uint4 Z = ((const uint4*)(WHH + (size_t)(Hn + j)*Hn))[lane];
                const uint4 N = ((const uint4*)(WHH + (size_t)(2*Hn + j)*Hn))[lane];
                ghr[k] = wave_sum(dot8h(R, HH, 0.0f));
                ghz[k] = wave_sum(dot8h(Z, HH, 0.0f));
                ghn[k] = wave_sum(dot8h(N, HH, 0.0f));
            }
        }
        sib_wait(cntA, tgtc);

        // assemble full x
        if (wid < 3) {
            const int qq = (q + 1 + wid) & 3;
            x32[qq*64 + lane] = ald(XEX + b*256 + qq*64 + lane);
        } else if (wid == 3) {
            x32[q*64 + lane] = (u32)xst[2*lane] | ((u32)xst[2*lane+1] << 16);
        }
        __syncthreads();

        // ---- P5: gi dots + gate combine -> h_new own quarter ----
        {
            const uint4 X = ((const uint4*)x32)[lane];
#pragma unroll
            for (int k = 0; k < 8; ++k) {
                const int j = j0 + wid*8 + k;
                const uint4 R = ((const uint4*)(WIH + (size_t)j*Hn))[lane];
                const uint4 Z = ((const uint4*)(WIH + (size_t)(Hn + j)*Hn))[lane];
                const uint4 N = ((const uint4*)(WIH + (size_t)(2*Hn + j)*Hn))[lane];
                const float gir = wave_sum(dot8h(R, X, 0.0f));
                const float giz = wave_sum(dot8h(Z, X, 0.0f));
                const float gin = wave_sum(dot8h(N, X, 0.0f));
                if (lane == 0) {
                    const float r = fast_sigmoid(gir + ghr[k] + bih[j] + bhh[j]);
                    const float z = fast_sigmoid(giz + ghz[k] + bih[Hn+j] + bhh[Hn+j]);
                    const float n = fast_tanh(gin + bih[2*Hn+j] + r*(ghn[k] + bhh[2*Hn+j]));
                    const float hv = (1.0f - z)*n + z*h_full[j];
                    h_full[j] = hv;
                    hn16[wid*8 + k] = f2h(hv);
                }
            }
        }
        __syncthreads();

        // ---- P6: logit partials over own j-quarter ----
        {
            const u32 hh = ((const u32*)hn16)[lane];
            for (int v = wid; v < Vn; v += 16) {
                const u32 w = ((const u32*)(WOUT + (size_t)v*Hn + j0))[lane];
                const float acc = wave_sum(dot2acc(w, hh, 0.0f));
                if (lane == 0) plog_s[v] = acc;
            }
        }
        __syncthreads();

        // publish partial logits + h quarter
        if (wid == 0) {
            if (lane < 50) {
                astf(PLOG + ((size_t)b*4 + q)*100 + 2*lane,     plog_s[2*lane]);
                astf(PLOG + ((size_t)b*4 + q)*100 + 2*lane + 1, plog_s[2*lane+1]);
            }
        } else if (wid == 1) {
            astf(HEXF + (size_t)b*Hn + j0 + 2*lane,     h_full[j0 + 2*lane]);
            astf(HEXF + (size_t)b*Hn + j0 + 2*lane + 1, h_full[j0 + 2*lane + 1]);
        } else if (wid == 2) {
            ast(HEXH + b*256 + q*64 + lane, (u32)hn16[2*lane] | ((u32)hn16[2*lane+1] << 16));
        }
        sib_arrive(cntB);
        sib_wait(cntB, tgtc);

        // assemble h; sibling 0 computes log-softmax and stores out[t]
        if (wid < 3) {
            const int qq = (q + 1 + wid) & 3;
            h_full[qq*128 + 2*lane]     = aldf(HEXF + (size_t)b*Hn + qq*128 + 2*lane);
            h_full[qq*128 + 2*lane + 1] = aldf(HEXF + (size_t)b*Hn + qq*128 + 2*lane + 1);
            hh32[qq*64 + lane] = ald(HEXH + b*256 + qq*64 + lane);
        } else if (wid == 3) {
            hh32[q*64 + lane] = (u32)hn16[2*lane] | ((u32)hn16[2*lane+1] << 16);
        } else if (wid == 4 && q == 0) {
            float a0 = 0.0f, a1 = 0.0f;
            if (lane < 50) {
                a0 = bout[2*lane];
                a1 = bout[2*lane+1];
#pragma unroll
                for (int qq = 0; qq < 4; ++qq) {
                    a0 += aldf(PLOG + ((size_t)b*4 + qq)*100 + 2*lane);
                    a1 += aldf(PLOG + ((size_t)b*4 + qq)*100 + 2*lane + 1);
                }
            }
            const float l0 = (lane < 50) ? a0 : -3.0e38f;
            const float l1 = (lane < 50) ? a1 : -3.0e38f;
            const float mx = wave_max(fmaxf(l0, l1));
            const float e0 = (lane < 50) ? __expf(l0 - mx) : 0.0f;
            const float e1 = (lane < 50) ? __expf(l1 - mx) : 0.0f;
            const float lse = mx + __logf(wave_sum(e0 + e1));
            float* op = out + ((size_t)b*TSn + t)*Vn;
            if (lane < 50) { op[2*lane] = l0 - lse; op[2*lane+1] = l1 - lse; }
        }
        __syncthreads();
    }
}

extern "C" void kernel_launch(void* const* d_in, const int* in_sizes, int n_in,
                              void* d_out, int out_size, void* d_ws, size_t ws_size,
                              hipStream_t stream) {
    const float* enc   = (const float*)d_in[0];
    const float* Wemb  = (const float*)d_in[1];
    const float* Wcomb = (const float*)d_in[2];
    const float* bcomb = (const float*)d_in[3];
    const float* Wih   = (const float*)d_in[4];
    const float* Whh   = (const float*)d_in[5];
    const float* bih   = (const float*)d_in[6];
    const float* bhh   = (const float*)d_in[7];
    const float* Wout  = (const float*)d_in[8];
    const float* bout  = (const float*)d_in[9];
    const float* wvat  = (const float*)d_in[10];
    const float* bvat  = (const float*)d_in[11];
    const int*   tgt   = (const int*)d_in[12];
    float* out = (float*)d_out;
    char*  ws  = (char*)d_ws;

    prep_conv<<<512, 256, 0, stream>>>(enc, Wcomb, Wih, Whh, Wout, ws);
    prep_emb2<<<64, 512, 0, stream>>>(Wemb, Wcomb, ws);

    void* args[] = { &bcomb, &bih, &bhh, &bout, &wvat, &bvat, &tgt, &out, &ws };
    hipLaunchCooperativeKernel((const void*)bahdanau_decoder,
                               dim3(256), dim3(1024), args, (size_t)(Sn*Hn*2), stream);
}